// Round 12
// baseline (21308.931 us; speedup 1.0000x reference)
//
#include <hip/hip_runtime.h>

#define T_   512
#define I_   64
#define R_   1024
#define O_   64
#define KK_  34      // K blocks of 32: 1024 state + 64 input
#define GRP_ 8       // blocks per exchange group (col-split)
#define POLL_MAX 65536  // bounded spin: never triggers when healthy; prevents device hang

typedef __attribute__((ext_vector_type(8))) short short8;   // 8 bf16
typedef __attribute__((ext_vector_type(4))) float float4v;  // MFMA acc

__device__ inline unsigned short f2bf(float x) {
  union { float f; unsigned u; } v; v.f = x;
  unsigned r = v.u + 0x7FFFu + ((v.u >> 16) & 1u);  // RNE
  return (unsigned short)(r >> 16);
}
__device__ inline float bf2f(unsigned short h) {
  union { unsigned u; float f; } v; v.u = ((unsigned)h) << 16;
  return v.f;
}
// fast tanh: 1 - 2/(1+e^{2x}); exact at 0, saturates correctly at +/-inf
__device__ inline float ftanh(float x) {
  float e = __expf(2.0f * x);
  return 1.0f - 2.0f / (e + 1.0f);
}

// frag-contiguous index for element (k, n) of packed weight Wt2
__device__ inline size_t wt2_idx(int k, int n) {
  return ((((size_t)(n >> 4) * KK_ + (k >> 5)) * 4 + ((k >> 3) & 3)) * 16 + (n & 15)) * 8 + (k & 7);
}

// Pack W (k<1024: W_res[k][n]; k>=1024: W_in[k-1024][n]) -> bf16 frag-contiguous.
__global__ void esn_prep_wt(const float* __restrict__ Wres, const float* __restrict__ Win,
                            unsigned short* __restrict__ Wt2) {
  __shared__ float tile[32][33];
  int nt = blockIdx.x, kt = blockIdx.y;
  int tx = threadIdx.x & 31;
  int ty = threadIdx.x >> 5;
  int k0 = kt * 32, n0 = nt * 32;
  #pragma unroll
  for (int s = 0; s < 4; ++s) {
    int k = k0 + ty + 8 * s;
    int n = n0 + tx;
    float v = (k < R_) ? Wres[(size_t)k * R_ + n] : Win[(size_t)(k - R_) * R_ + n];
    tile[ty + 8 * s][tx] = v;
  }
  __syncthreads();
  #pragma unroll
  for (int s = 0; s < 4; ++s) {
    int n = n0 + ty + 8 * s;
    int k = k0 + tx;
    Wt2[wt2_idx(k, n)] = f2bf(tile[tx][ty + 8 * s]);
  }
}

// zero the per-(group,step) barrier counters (ws is re-poisoned before every launch)
__global__ void esn_zero_cnt(int* __restrict__ cnt) {
  cnt[blockIdx.x * 1024 + threadIdx.x] = 0;
}

// Weight-stationary recurrence: 256 blocks = 32 batch-groups (gb) x 8 col-groups (gc).
// Block: 512 threads (8 waves). Wave w holds W cols [gc*128 + w*16, +16) x K=1088 in
// 136 VGPRs for the whole kernel. Per step: MFMA (reg W x LDS state) -> tanh ->
// publish 4KB bf16 tile -> release atomicAdd -> BOUNDED poll of group counter ->
// threadfence -> restage 32KB row-slice from L3 into LDS. Parity double-buffer.
__global__ __launch_bounds__(512, 2) void esn_recur_x(
    const float* __restrict__ input, const unsigned short* __restrict__ Wt2,
    const float* __restrict__ Wout, float* __restrict__ out,
    unsigned short* __restrict__ sbuf, int* __restrict__ cnt) {
  __shared__ unsigned short aLds[KK_ * 512];  // [34][4][16][8] shorts = 34816 B

  const int tid  = threadIdx.x;
  const int lane = tid & 63;
  const int w    = tid >> 6;      // wave 0..7 -> one 16-col n-tile
  const int nl   = lane & 15;
  const int kgrp = lane >> 4;
  const int bid  = blockIdx.x;
  const int gb   = bid & 31;      // batch group (keeps group on one XCD under bid%8)
  const int gc   = bid >> 5;      // col group 0..7
  const int bg0  = gb * 16;

  // --- W slice -> registers (static-indexed, stays in VGPRs)
  const int nt = gc * 8 + w;
  const unsigned short* bBase = Wt2 + (size_t)nt * 17408 + kgrp * 128 + nl * 8;
  short8 wfrag[KK_];
  #pragma unroll
  for (int kk = 0; kk < KK_; ++kk) wfrag[kk] = *(const short8*)(bBase + kk * 512);

  // --- u staging role: thread -> (m_u = tid>>5, i0 = (tid&31)*2), 2 bf16 per thread
  const int m_u = tid >> 5;
  const int i0  = (tid & 31) * 2;
  const float* inp_u = input + (size_t)(bg0 + m_u) * T_ * I_ + i0;
  const int k_u = R_ + i0;
  const int idxu = (((k_u >> 5) * 4 + ((k_u >> 3) & 3)) * 16 + m_u) * 8 + (k_u & 7);

  // zero state region (32 KB), stage u_0
  int* zp = (int*)aLds;
  #pragma unroll
  for (int s = 0; s < 16; ++s) zp[tid + 512 * s] = 0;
  {
    float2 u0 = *(const float2*)inp_u;
    *(unsigned*)(aLds + idxu) = (unsigned)f2bf(u0.x) | ((unsigned)f2bf(u0.y) << 16);
  }
  __syncthreads();

  const unsigned short* aBase = aLds + (kgrp * 16 + nl) * 8;
  const int n_g = gc * 128 + w * 16 + nl;  // this lane's output col (next-step k)
  const int pub = (((n_g >> 5) * 4 + ((n_g >> 3) & 3)) * 16 + kgrp * 4) * 8 + (n_g & 7);
  int* const cbase = cnt + gb * T_;
  unsigned short* const sb0 = sbuf + (size_t)gb * 16384;            // parity 0 slice
  unsigned short* const sb1 = sbuf + 524288 + (size_t)gb * 16384;   // parity 1 slice

  float s_local[4] = {0.f, 0.f, 0.f, 0.f};

  for (int t = 0; t < T_; ++t) {
    // prefetch u_{t+1} (register; immune to later cache invalidation)
    const int tn = (t + 1 < T_) ? t + 1 : T_ - 1;
    float2 un = *(const float2*)(inp_u + (size_t)tn * I_);

    float4v acc = {0.f, 0.f, 0.f, 0.f};
    #pragma unroll
    for (int kk = 0; kk < KK_; ++kk) {
      short8 a = *(const short8*)(aBase + kk * 512);
      acc = __builtin_amdgcn_mfma_f32_16x16x32_bf16(a, wfrag[kk], acc, 0, 0, 0);
    }

    // leak + tanh + publish bf16 tile to parity (t+1)&1
    unsigned short* dst = ((t & 1) ? sb0 : sb1) + pub;
    #pragma unroll
    for (int r = 0; r < 4; ++r) {
      float ns = 0.5f * s_local[r] + 0.5f * ftanh(acc[r]);
      s_local[r] = ns;
      dst[r * 8] = f2bf(ns);
    }
    __syncthreads();  // drains each wave's vmem stores before the release
    if (tid == 0)
      __hip_atomic_fetch_add(cbase + t, 1, __ATOMIC_RELEASE, __HIP_MEMORY_SCOPE_AGENT);

    if (t + 1 < T_) {
      if (tid == 0) {
        int guard = 0;  // bounded: healthy wait is <<1ms; guard only fires if handshake broken
        while (__hip_atomic_load(cbase + t, __ATOMIC_RELAXED, __HIP_MEMORY_SCOPE_AGENT) < GRP_
               && guard < POLL_MAX) {
          __builtin_amdgcn_s_sleep(1);
          ++guard;
        }
      }
      __syncthreads();
      __threadfence();  // agent acquire: invalidate L1/L2 so stage reads fresh state
      const unsigned short* src = (t & 1) ? sb0 : sb1;  // parity (t+1)&1
      #pragma unroll
      for (int c = 0; c < 4; ++c) {
        short8 v = *(const short8*)(src + (c * 512 + tid) * 8);
        *(short8*)(aLds + (c * 512 + tid) * 8) = v;
      }
      *(unsigned*)(aLds + idxu) = (unsigned)f2bf(un.x) | ((unsigned)f2bf(un.y) << 16);
      __syncthreads();
    }
  }

  // --- epilogue: col-group 0 of each batch-group computes out = state_512 @ Wout
  if (gc == 0) {
    if (tid == 0) {
      int guard = 0;
      while (__hip_atomic_load(cbase + (T_ - 1), __ATOMIC_RELAXED, __HIP_MEMORY_SCOPE_AGENT) < GRP_
             && guard < POLL_MAX) {
        __builtin_amdgcn_s_sleep(1);
        ++guard;
      }
    }
    __syncthreads();
    __threadfence();
    #pragma unroll
    for (int c = 0; c < 4; ++c) {  // state_512 lives in parity 0
      short8 v = *(const short8*)(sb0 + (c * 512 + tid) * 8);
      *(short8*)(aLds + (c * 512 + tid) * 8) = v;
    }
    __syncthreads();
    const int m = tid >> 5;
    const int o0 = (tid & 31) * 2;
    float a0 = 0.f, a1 = 0.f;
    for (int k = 0; k < R_; ++k) {
      float sv = bf2f(aLds[(((k >> 5) * 4 + ((k >> 3) & 3)) * 16 + m) * 8 + (k & 7)]);
      const float* wr = Wout + (size_t)k * O_ + o0;
      a0 += sv * wr[0];
      a1 += sv * wr[1];
    }
    float2 res; res.x = a0; res.y = a1;
    *(float2*)(out + (size_t)(bg0 + m) * O_ + o0) = res;
  }
}

extern "C" void kernel_launch(void* const* d_in, const int* in_sizes, int n_in,
                              void* d_out, int out_size, void* d_ws, size_t ws_size,
                              hipStream_t stream) {
  const float* input = (const float*)d_in[0];
  const float* Wres  = (const float*)d_in[1];
  const float* Win   = (const float*)d_in[2];
  const float* Wout  = (const float*)d_in[3];
  float* out = (float*)d_out;

  // ws: Wt2 2,228,224 B | sbuf 2 x 1,048,576 B | cnt 65,536 B  => ~4.4 MB
  char* ws = (char*)d_ws;
  unsigned short* Wt2  = (unsigned short*)ws;
  unsigned short* sbuf = (unsigned short*)(ws + 2228224);
  int*            cnt  = (int*)(ws + 2228224 + 2097152);

  esn_prep_wt<<<dim3(32, 34), 256, 0, stream>>>(Wres, Win, Wt2);
  esn_zero_cnt<<<16, 1024, 0, stream>>>(cnt);

  void* args[] = { (void*)&input, (void*)&Wt2, (void*)&Wout, (void*)&out,
                   (void*)&sbuf, (void*)&cnt };
  hipLaunchCooperativeKernel((void*)esn_recur_x, dim3(256), dim3(512), args, 0, stream);
}